// Round 4
// baseline (107.873 us; speedup 1.0000x reference)
//
#include <hip/hip_runtime.h>

#define NB 16
#define NCH 64
#define NT 2048
#define SPLIT 4
#define JQ (NT / SPLIT)     // 512 j per wave
#define NTILE (JQ / 64)     // 8 tiles of 64
#define PSTR 72             // P row stride (shorts): 144 B rows

typedef __attribute__((ext_vector_type(8))) short bf8;
typedef __attribute__((ext_vector_type(4))) short bf4;
typedef __attribute__((ext_vector_type(4))) float f4;

static __device__ __forceinline__ short f2b(float f) {
    unsigned u = __float_as_uint(f);
    u += 0x7fffu + ((u >> 16) & 1u);
    return (short)(u >> 16);
}

// ---- prep: Xs[b][t] = sum_c x ; xT[b][t][c] bf16 ; xn[b][c][t] bf16 ----
__global__ __launch_bounds__(256)
void prep_k(const float* __restrict__ x, float* __restrict__ Xs,
            short* __restrict__ xT, short* __restrict__ xn) {
    __shared__ float T[NCH][65];
    const int b = blockIdx.y, t0 = blockIdx.x * 64;
    const int tid = threadIdx.x;
    const float* xb = x + (size_t)b * NCH * NT;

    const int tt = (tid & 15) * 4;
    #pragma unroll
    for (int co = 0; co < 4; ++co) {
        int c = co * 16 + (tid >> 4);
        float4 v = *reinterpret_cast<const float4*>(&xb[(size_t)c * NT + t0 + tt]);
        T[c][tt] = v.x; T[c][tt + 1] = v.y; T[c][tt + 2] = v.z; T[c][tt + 3] = v.w;
        bf4 w; w[0] = f2b(v.x); w[1] = f2b(v.y); w[2] = f2b(v.z); w[3] = f2b(v.w);
        *reinterpret_cast<bf4*>(&xn[((size_t)b * NCH + c) * NT + t0 + tt]) = w;
    }
    __syncthreads();
    if (tid < 64) {
        float s = 0.f;
        #pragma unroll
        for (int c = 0; c < NCH; ++c) s += T[c][tid];
        Xs[b * NT + t0 + tid] = s;
    }
    const int row = tid >> 2, cs = (tid & 3) * 16;
    bf8 v0, v1;
    #pragma unroll
    for (int u = 0; u < 8; ++u) v0[u] = f2b(T[cs + u][row]);
    #pragma unroll
    for (int u = 0; u < 8; ++u) v1[u] = f2b(T[cs + 8 + u][row]);
    short* dst = xT + ((size_t)b * NT + t0 + row) * NCH + cs;
    *reinterpret_cast<bf8*>(dst) = v0;
    *reinterpret_cast<bf8*>(dst + 8) = v1;
}

// ---- fused, barrier-free streaming: each wave owns 32 i-rows x one j-quarter ----
__global__ __launch_bounds__(256)
void attn4_k(const float* __restrict__ x,
             const float* __restrict__ w1, const float* __restrict__ b1p,
             const float* __restrict__ w2, const float* __restrict__ b2p,
             const float* __restrict__ gp,
             const float* __restrict__ Xs, const short* __restrict__ xT,
             const short* __restrict__ xn,
             float* __restrict__ out) {
    // pool overlays: per-wave P scratch (4*32*72 shorts = 18432 B) then mergeAcc (4*64*32 f32 = 32768 B)
    __shared__ float pool[8192];
    __shared__ float mergeMn[4][2][16];
    __shared__ float mergeMx[4][2][16];
    __shared__ float mergePS[4][2][16];

    const int b  = blockIdx.y;
    const int i0 = blockIdx.x * 32;
    const int tid  = threadIdx.x;
    const int h    = tid >> 6;      // j-quarter owned by this wave
    const int lane = tid & 63;
    const int lq = lane >> 4, ln = lane & 15;

    short* Pw = reinterpret_cast<short*>(pool) + h * 32 * PSTR;
    float* mergeAcc = pool;         // [w][c(64)][i(32)]

    float s11 = 0.f, s1b2 = 0.f, s2b1 = 0.f, sbb = 0.f;
    #pragma unroll
    for (int f = 0; f < 8; ++f) {
        s11  += w1[f] * w2[f];
        s1b2 += w1[f] * b2p[f];
        s2b1 += b1p[f] * w2[f];
        sbb  += b1p[f] * b2p[f];
    }
    const float c0 = (float)NCH * sbb;
    const float g  = gp[0];

    const short* xTb = xT + (size_t)b * NT * NCH;
    const short* xnb = xn + (size_t)b * NCH * NT;
    const float* xb  = x + (size_t)b * NCH * NT;

    // constant B-frags (i-side of Gram^T): B[k=c][n=i-local], i = i0 + s*16 + ln
    bf8 Bg[2][2];
    #pragma unroll
    for (int s = 0; s < 2; ++s)
        #pragma unroll
        for (int kk = 0; kk < 2; ++kk)
            Bg[s][kk] = *reinterpret_cast<const bf8*>(
                xTb + (size_t)(i0 + s * 16 + ln) * NCH + kk * 32 + lq * 8);

    float cs0[2];
    #pragma unroll
    for (int s = 0; s < 2; ++s)
        cs0[s] = fmaf(s1b2, Xs[b * NT + i0 + s * 16 + ln], c0);

    float rmin[2] = {3.0e38f, 3.0e38f}, rmax[2] = {-3.0e38f, -3.0e38f};

    // ---------- pass 1: min/max over this wave's j-quarter (no barriers) ----------
    for (int t = 0; t < NTILE; ++t) {
        const int j0t = h * JQ + t * 64;
        const short* abase = xTb + (size_t)j0t * NCH;
        float XjA[4][4];
        #pragma unroll
        for (int jn = 0; jn < 4; ++jn) {
            float4 v = *reinterpret_cast<const float4*>(Xs + b * NT + j0t + jn * 16 + lq * 4);
            XjA[jn][0] = v.x; XjA[jn][1] = v.y; XjA[jn][2] = v.z; XjA[jn][3] = v.w;
        }
        #pragma unroll
        for (int jn = 0; jn < 4; ++jn) {
            const short* ap = abase + (size_t)(jn * 16 + ln) * NCH + lq * 8;
            bf8 a0 = *reinterpret_cast<const bf8*>(ap);
            bf8 a1 = *reinterpret_cast<const bf8*>(ap + 32);
            #pragma unroll
            for (int s = 0; s < 2; ++s) {
                f4 acc = {0.f, 0.f, 0.f, 0.f};
                acc = __builtin_amdgcn_mfma_f32_16x16x32_bf16(a0, Bg[s][0], acc, 0, 0, 0);
                acc = __builtin_amdgcn_mfma_f32_16x16x32_bf16(a1, Bg[s][1], acc, 0, 0, 0);
                #pragma unroll
                for (int r = 0; r < 4; ++r) {
                    float e = fmaf(s11, acc[r], fmaf(s2b1, XjA[jn][r], cs0[s]));
                    rmin[s] = fminf(rmin[s], e);
                    rmax[s] = fmaxf(rmax[s], e);
                }
            }
        }
    }

    // reduce over lq, merge quarters
    #pragma unroll
    for (int s = 0; s < 2; ++s) {
        rmin[s] = fminf(rmin[s], __shfl_xor(rmin[s], 16, 64));
        rmin[s] = fminf(rmin[s], __shfl_xor(rmin[s], 32, 64));
        rmax[s] = fmaxf(rmax[s], __shfl_xor(rmax[s], 16, 64));
        rmax[s] = fmaxf(rmax[s], __shfl_xor(rmax[s], 32, 64));
    }
    if (lane < 16) {
        #pragma unroll
        for (int s = 0; s < 2; ++s) {
            mergeMn[h][s][ln] = rmin[s];
            mergeMx[h][s][ln] = rmax[s];
        }
    }
    __syncthreads();
    float mn[2], inv[2];
    #pragma unroll
    for (int s = 0; s < 2; ++s) {
        float a = mergeMn[0][s][ln], bb = mergeMx[0][s][ln];
        #pragma unroll
        for (int w = 1; w < 4; ++w) {
            a  = fminf(a, mergeMn[w][s][ln]);
            bb = fmaxf(bb, mergeMx[w][s][ln]);
        }
        mn[s]  = a;
        inv[s] = 1.f / (bb - a + 1e-8f);
    }

    f4 macc[4][2];
    #pragma unroll
    for (int cb = 0; cb < 4; ++cb)
        #pragma unroll
        for (int s = 0; s < 2; ++s)
            macc[cb][s] = (f4){0.f, 0.f, 0.f, 0.f};
    float ps[2] = {0.f, 0.f};

    // ---------- pass 2: Gram^T -> exp -> wave-private P -> mixed MFMA ----------
    for (int t = 0; t < NTILE; ++t) {
        const int j0t = h * JQ + t * 64;
        const short* abase = xTb + (size_t)j0t * NCH;
        float XjA[4][4];
        #pragma unroll
        for (int jn = 0; jn < 4; ++jn) {
            float4 v = *reinterpret_cast<const float4*>(Xs + b * NT + j0t + jn * 16 + lq * 4);
            XjA[jn][0] = v.x; XjA[jn][1] = v.y; XjA[jn][2] = v.z; XjA[jn][3] = v.w;
        }
        #pragma unroll
        for (int jn = 0; jn < 4; ++jn) {
            const short* ap = abase + (size_t)(jn * 16 + ln) * NCH + lq * 8;
            bf8 a0 = *reinterpret_cast<const bf8*>(ap);
            bf8 a1 = *reinterpret_cast<const bf8*>(ap + 32);
            #pragma unroll
            for (int s = 0; s < 2; ++s) {
                f4 acc = {0.f, 0.f, 0.f, 0.f};
                acc = __builtin_amdgcn_mfma_f32_16x16x32_bf16(a0, Bg[s][0], acc, 0, 0, 0);
                acc = __builtin_amdgcn_mfma_f32_16x16x32_bf16(a1, Bg[s][1], acc, 0, 0, 0);
                float p[4];
                #pragma unroll
                for (int r = 0; r < 4; ++r) {
                    float e = fmaf(s11, acc[r], fmaf(s2b1, XjA[jn][r], cs0[s]));
                    p[r] = __expf((e - mn[s]) * inv[s]);
                    ps[s] += p[r];
                }
                bf4 wv; wv[0] = f2b(p[0]); wv[1] = f2b(p[1]); wv[2] = f2b(p[2]); wv[3] = f2b(p[3]);
                *reinterpret_cast<bf4*>(&Pw[(s * 16 + ln) * PSTR + jn * 16 + lq * 4]) = wv;
            }
        }
        // mixed: macc[c][i] += sum_j xn[c][j] * P[i][j]   (wave-private P, no barrier)
        bf8 Pf[2][2];
        #pragma unroll
        for (int s = 0; s < 2; ++s)
            #pragma unroll
            for (int kk = 0; kk < 2; ++kk)
                Pf[s][kk] = *reinterpret_cast<const bf8*>(
                    &Pw[(s * 16 + ln) * PSTR + kk * 32 + lq * 8]);
        #pragma unroll
        for (int cb = 0; cb < 4; ++cb) {
            const short* mp = xnb + (size_t)(cb * 16 + ln) * NT + j0t + lq * 8;
            bf8 m0 = *reinterpret_cast<const bf8*>(mp);
            bf8 m1 = *reinterpret_cast<const bf8*>(mp + 32);
            #pragma unroll
            for (int s = 0; s < 2; ++s) {
                macc[cb][s] = __builtin_amdgcn_mfma_f32_16x16x32_bf16(m0, Pf[s][0], macc[cb][s], 0, 0, 0);
                macc[cb][s] = __builtin_amdgcn_mfma_f32_16x16x32_bf16(m1, Pf[s][1], macc[cb][s], 0, 0, 0);
            }
        }
    }

    // ---------- merge across quarters ----------
    #pragma unroll
    for (int s = 0; s < 2; ++s) {
        ps[s] += __shfl_xor(ps[s], 16, 64);
        ps[s] += __shfl_xor(ps[s], 32, 64);
    }
    if (lane < 16) {
        #pragma unroll
        for (int s = 0; s < 2; ++s) mergePS[h][s][ln] = ps[s];
    }
    __syncthreads();   // all waves done with Pw (overlay) + PS written
    #pragma unroll
    for (int cb = 0; cb < 4; ++cb)
        #pragma unroll
        for (int s = 0; s < 2; ++s)
            #pragma unroll
            for (int r = 0; r < 4; ++r)
                mergeAcc[((size_t)h * 64 + cb * 16 + lq * 4 + r) * 32 + s * 16 + ln] = macc[cb][s][r];
    __syncthreads();

    float rowSum[2];
    #pragma unroll
    for (int s = 0; s < 2; ++s) {
        float v = 0.f;
        #pragma unroll
        for (int w = 0; w < 4; ++w) v += mergePS[w][s][ln];
        rowSum[s] = v;
    }

    // wave h writes c-range [h*16, h*16+16)
    #pragma unroll
    for (int s = 0; s < 2; ++s) {
        const int i = i0 + s * 16 + ln;
        #pragma unroll
        for (int r = 0; r < 4; ++r) {
            const int c = h * 16 + lq * 4 + r;
            float tot = 0.f;
            #pragma unroll
            for (int w = 0; w < 4; ++w)
                tot += mergeAcc[((size_t)w * 64 + c) * 32 + s * 16 + ln];
            out[((size_t)b * NCH + c) * NT + i] = g * tot / rowSum[s] + xb[(size_t)c * NT + i];
        }
    }
}

extern "C" void kernel_launch(void* const* d_in, const int* in_sizes, int n_in,
                              void* d_out, int out_size, void* d_ws, size_t ws_size,
                              hipStream_t stream) {
    const float* x     = (const float*)d_in[0];
    const float* w1    = (const float*)d_in[1];
    const float* b1    = (const float*)d_in[2];
    const float* w2    = (const float*)d_in[3];
    const float* b2    = (const float*)d_in[4];
    const float* gamma = (const float*)d_in[5];
    float* out = (float*)d_out;

    float* Xs = (float*)d_ws;                                        // 128 KB
    short* xT = (short*)((char*)d_ws + (size_t)NB * NT * 4);         // 4 MB
    short* xn = (short*)((char*)d_ws + (size_t)NB * NT * 4
                         + (size_t)NB * NT * NCH * 2);               // 4 MB

    hipLaunchKernelGGL(prep_k, dim3(NT / 64, NB), dim3(256), 0, stream, x, Xs, xT, xn);
    hipLaunchKernelGGL(attn4_k, dim3(NT / 32, NB), dim3(256), 0, stream,
                       x, w1, b1, w2, b2, gamma, Xs, xT, xn, out);
}